// Round 4
// baseline (458.768 us; speedup 1.0000x reference)
//
#include <hip/hip_runtime.h>

// GNN NNConv, N=25000, E=50000, C=49, 3 live layers (layer 3 of ref is dead code).
// msg[e,o] = sum_k t[e,k]*U_k[src,o] + U_b[src,o];  U per NODE (GEMM); edges are
// CSR-gathered (no atomics in the per-layer hot path).
// PK record per edge per layer: {src_as_float, t0, t1, t2} (16B, s_load_dwordx4).

#define N 25000
#define E 50000
#define C 49
#define C2 196
#define SLOPE 0.01f
#define GK 8              // nodes per wave in gathpre
#define NPB 32            // nodes per block in gathpre (4 waves * GK)

__device__ __forceinline__ float leaky(float v) { return v > 0.f ? v : SLOPE * v; }
#define RFL(x) __builtin_amdgcn_readfirstlane(x)

__global__ void deg_kernel(const int* __restrict__ ei, float* __restrict__ deg) {
    int e = blockIdx.x * 256 + threadIdx.x;
    if (e < E) atomicAdd(&deg[ei[E + e]], 1.0f);
}

// exclusive prefix over deg -> rowptr[0..N]; single block, 1024 threads x 25 bins
__global__ __launch_bounds__(1024) void scan_kernel(const float* __restrict__ deg,
                                                    int* __restrict__ rowptr) {
    __shared__ int part[1024];
    int t = threadIdx.x;
    int base = t * 25;
    int loc[25];
    int run = 0;
#pragma unroll
    for (int i = 0; i < 25; i++) {
        loc[i] = run;
        int idx = base + i;
        run += (idx < N) ? (int)deg[idx] : 0;
    }
    part[t] = run;
    __syncthreads();
    for (int off = 1; off < 1024; off <<= 1) {
        int v = (t >= off) ? part[t - off] : 0;
        __syncthreads();
        part[t] += v;
        __syncthreads();
    }
    int pbase = (t == 0) ? 0 : part[t - 1];
#pragma unroll
    for (int i = 0; i < 25; i++) {
        int idx = base + i;
        if (idx <= N) rowptr[idx] = pbase + loc[i];
    }
}

// CSR scatter + edge-MLP: per edge, pos = rowptr[dst] + cnt[dst]++;
// PK[l][pos] = {src, relu(ea@W1[l]+b1[l]) (3 floats)}
__global__ void scatter_kernel(const int* __restrict__ ei, const float* __restrict__ ea,
                               const float* __restrict__ w1, const float* __restrict__ b1,
                               const int* __restrict__ rowptr, int* __restrict__ cnt,
                               float* __restrict__ PK) {
    int e = blockIdx.x * 256 + threadIdx.x;
    if (e >= E) return;
    int s = ei[e], d = ei[E + e];
    int pos = rowptr[d] + atomicAdd(&cnt[d], 1);
    float a[10];
#pragma unroll
    for (int j = 0; j < 10; j++) a[j] = ea[e * 10 + j];
#pragma unroll
    for (int l = 0; l < 3; l++) {
        float tk[3];
#pragma unroll
        for (int k = 0; k < 3; k++) {
            float acc = b1[l * 3 + k];
#pragma unroll
            for (int j = 0; j < 10; j++) acc += a[j] * w1[l * 30 + j * 3 + k];
            tk[k] = fmaxf(acc, 0.f);
        }
        float4 rec = make_float4(__int_as_float(s), tk[0], tk[1], tk[2]);
        *reinterpret_cast<float4*>(PK + ((size_t)l * E + pos) * 4) = rec;
    }
}

// fused: h = leaky(x@lin_w+lin_b) -> h, out(JK init), then U0 = h @ [W2|b2]
__global__ __launch_bounds__(256) void h2u0_kernel(const float* __restrict__ x,
                                                   const float* __restrict__ lw,
                                                   const float* __restrict__ lb,
                                                   const float* __restrict__ w2,
                                                   const float* __restrict__ b2,
                                                   float* __restrict__ h,
                                                   float* __restrict__ out,
                                                   float* __restrict__ U) {
    __shared__ float xs[64][56];
    __shared__ float hs[64][52];
    int t = threadIdx.x, base = blockIdx.x * 64;
    int nv = min(64, N - base);
    for (int e = t; e < nv * 56; e += 256) xs[e / 56][e % 56] = x[(size_t)base * 56 + e];
    for (int j = t; j < 64 * 3; j += 256) hs[j / 3][C + (j % 3)] = 0.f;
    __syncthreads();
    int r = t >> 6, c = t & 63;
    if (c < C) {
        float w[56];
#pragma unroll
        for (int i = 0; i < 56; i++) w[i] = lw[i * C + c];
        float bias = lb[c];
        for (int n = r; n < nv; n += 4) {
            float acc = bias;
#pragma unroll
            for (int i4 = 0; i4 < 14; i4++) {
                float4 hv = *reinterpret_cast<const float4*>(&xs[n][i4 * 4]);
                acc += hv.x * w[i4 * 4] + hv.y * w[i4 * 4 + 1] + hv.z * w[i4 * 4 + 2] +
                       hv.w * w[i4 * 4 + 3];
            }
            acc = leaky(acc);
            h[(size_t)(base + n) * C + c] = acc;
            out[(size_t)(base + n) * C + c] = acc;
            hs[n][c] = acc;
        }
    }
    __syncthreads();
    if (t < C2) {
        int k = t / C, o = t % C;
        const float* Wp = (k < 3 ? w2 + k * (C * C) : b2) + o;
        float w[52];
#pragma unroll
        for (int i = 0; i < C; i++) w[i] = Wp[i * C];
        w[49] = w[50] = w[51] = 0.f;
        for (int n = 0; n < nv; n++) {
            float acc = 0.f;
#pragma unroll
            for (int i4 = 0; i4 < 13; i4++) {
                float4 hv = *reinterpret_cast<const float4*>(&hs[n][i4 * 4]);
                acc += hv.x * w[i4 * 4] + hv.y * w[i4 * 4 + 1] + hv.z * w[i4 * 4 + 2] +
                       hv.w * w[i4 * 4 + 3];
            }
            U[(size_t)(base + n) * C2 + t] = acc;
        }
    }
}

// BN(prev pre, via st scale/shift) -> hnext + JK out, then U = hnext @ [W2|b2]
__global__ __launch_bounds__(256) void uni_kernel(const float* __restrict__ in,
                                                  const float* __restrict__ st,
                                                  const float* __restrict__ w2,
                                                  const float* __restrict__ b2,
                                                  float* __restrict__ hnext,
                                                  float* __restrict__ out,
                                                  float* __restrict__ U) {
    __shared__ float hs[64][52];
    __shared__ float scl[52], sft[52];
    int t = threadIdx.x, base = blockIdx.x * 64;
    int nv = min(64, N - base);
    if (t < C) { scl[t] = st[128 + t]; sft[t] = st[192 + t]; }
    for (int j = t; j < 64 * 3; j += 256) hs[j / 3][C + j % 3] = 0.f;
    __syncthreads();
    for (int e = t; e < nv * C; e += 256) {
        int n = e / C, i = e % C;
        float v = in[(size_t)base * C + e];
        v = leaky(v * scl[i] + sft[i]);
        hnext[(size_t)base * C + e] = v;
        out[(size_t)base * C + e] += v;
        hs[n][i] = v;
    }
    __syncthreads();
    if (t < C2) {
        int k = t / C, o = t % C;
        const float* Wp = (k < 3 ? w2 + k * (C * C) : b2) + o;
        float w[52];
#pragma unroll
        for (int i = 0; i < C; i++) w[i] = Wp[i * C];
        w[49] = w[50] = w[51] = 0.f;
        for (int n = 0; n < nv; n++) {
            float acc = 0.f;
#pragma unroll
            for (int i4 = 0; i4 < 13; i4++) {
                float4 hv = *reinterpret_cast<const float4*>(&hs[n][i4 * 4]);
                acc += hv.x * w[i4 * 4] + hv.y * w[i4 * 4 + 1] + hv.z * w[i4 * 4 + 2] +
                       hv.w * w[i4 * 4 + 3];
            }
            U[(size_t)(base + n) * C2 + t] = acc;
        }
    }
}

// CSR gather + root GEMV + bias => pre; per-channel stats; last block finalizes BN
__global__ __launch_bounds__(256) void gathpre_kernel(
    const int* __restrict__ rowptr, const float* __restrict__ PK,
    const float* __restrict__ U, const float* __restrict__ deg,
    const float* __restrict__ h, const float* __restrict__ rw,
    const float* __restrict__ cb, const float* __restrict__ gm,
    const float* __restrict__ bt, float* __restrict__ pre,
    float* __restrict__ st, int nblocks) {
    __shared__ float red[8][64];
    __shared__ int last;
    int t = threadIdx.x;
    int wv = t >> 6, c = t & 63;
    int n0 = blockIdx.x * NPB + wv * GK;
    float w[C];
    float bias = 0.f;
    if (c < C) {
#pragma unroll
        for (int i = 0; i < C; i++) w[i] = rw[i * C + c];
        bias = cb[c];
    }
    float s = 0.f, q = 0.f;
    int nend = min(n0 + GK, N);
    for (int n = n0; n < nend; n++) {
        int nu = RFL(n);
        if (c < C) {
            int j0 = RFL(rowptr[nu]);
            int j1 = RFL(rowptr[nu + 1]);
            float acc = 0.f;
            for (int j = j0; j < j1; j++) {
                float4 m = *reinterpret_cast<const float4*>(PK + (size_t)j * 4);
                int sidx = RFL(__float_as_int(m.x));
                const float* u = U + (size_t)sidx * C2;
                acc += m.y * u[c] + m.z * u[C + c] + m.w * u[98 + c] + u[147 + c];
            }
            float inv = 1.0f / fmaxf(deg[nu], 1.0f);
            acc = acc * inv + bias;
            const float* hrow = h + (size_t)nu * C;
#pragma unroll
            for (int i = 0; i < C; i++) acc += hrow[i] * w[i];
            pre[(size_t)nu * C + c] = acc;
            s += acc;
            q += acc * acc;
        }
    }
    red[wv][c] = s;
    red[4 + wv][c] = q;
    __syncthreads();
    if (t < C) {
        float S = red[0][t] + red[1][t] + red[2][t] + red[3][t];
        float Q = red[4][t] + red[5][t] + red[6][t] + red[7][t];
        atomicAdd(&st[t], S);
        atomicAdd(&st[64 + t], Q);
    }
    __threadfence();
    if (t == 0) last = (atomicAdd((int*)(st + 250), 1) == nblocks - 1) ? 1 : 0;
    __syncthreads();
    if (last && t < C) {
        float S = atomicAdd(&st[t], 0.0f);   // coherent read-back
        float Q = atomicAdd(&st[64 + t], 0.0f);
        float mu = S * (1.0f / N);
        float var = Q * (1.0f / N) - mu * mu;
        float sc = rsqrtf(var + 1e-5f) * gm[t];
        st[128 + t] = sc;
        st[192 + t] = bt[t] - mu * sc;
    }
}

// last layer: out += leaky(pre*sc+sh)
__global__ void fnorm_kernel(const float* __restrict__ pre, const float* __restrict__ st,
                             float* __restrict__ out) {
    int idx = blockIdx.x * 256 + threadIdx.x;
    if (idx >= N * C) return;
    int c = idx % C;
    out[idx] += leaky(pre[idx] * st[128 + c] + st[192 + c]);
}

extern "C" void kernel_launch(void* const* d_in, const int* in_sizes, int n_in,
                              void* d_out, int out_size, void* d_ws, size_t ws_size,
                              hipStream_t stream) {
    const float* x  = (const float*)d_in[0];
    const int* ei   = (const int*)d_in[1];
    const float* ea = (const float*)d_in[2];
    const float* lw = (const float*)d_in[3];
    const float* lb = (const float*)d_in[4];
    const float* w1 = (const float*)d_in[5];
    const float* b1 = (const float*)d_in[6];
    const float* w2 = (const float*)d_in[7];
    const float* b2 = (const float*)d_in[8];
    const float* rw = (const float*)d_in[9];
    const float* cb = (const float*)d_in[10];
    const float* gm = (const float*)d_in[11];
    const float* bt = (const float*)d_in[12];
    float* out = (float*)d_out;

    float* ws     = (float*)d_ws;
    float* deg    = ws;                       // N
    int*   cnt    = (int*)(deg + N);          // N
    float* st     = deg + 2 * N;              // 768 (layer l at st+256*l; ctr at +250)
    int*   rowptr = (int*)(st + 768);         // N+1
    float* PK     = (float*)(rowptr + N + 1); // 3*E*4
    float* agg    = PK + (size_t)12 * E;      // N*C  (pre)
    float* hA     = agg + (size_t)N * C;      // N*C
    float* hB     = hA + (size_t)N * C;       // N*C
    float* U      = hB + (size_t)N * C;       // N*C2

    hipMemsetAsync(deg, 0, (size_t)(2 * N + 768) * sizeof(float), stream);
    deg_kernel<<<(E + 255) / 256, 256, 0, stream>>>(ei, deg);
    scan_kernel<<<1, 1024, 0, stream>>>(deg, rowptr);
    scatter_kernel<<<(E + 255) / 256, 256, 0, stream>>>(ei, ea, w1, b1, rowptr, cnt, PK);
    h2u0_kernel<<<(N + 63) / 64, 256, 0, stream>>>(x, lw, lb, w2, b2, hA, out, U);

    const int GPB = (N + NPB - 1) / NPB;  // gathpre grid
    float* cur = hA;
    float* nxt = hB;
    for (int l = 0; l < 3; l++) {
        if (l > 0) {
            uni_kernel<<<(N + 63) / 64, 256, 0, stream>>>(
                agg, st + (l - 1) * 256, w2 + (size_t)l * 3 * C * C, b2 + (size_t)l * C * C,
                nxt, out, U);
            float* tmp = cur; cur = nxt; nxt = tmp;
        }
        gathpre_kernel<<<GPB, 256, 0, stream>>>(
            rowptr, PK + (size_t)l * E * 4, U, deg, cur, rw + (size_t)l * C * C,
            cb + l * C, gm + l * C, bt + l * C, agg, st + l * 256, GPB);
    }
    fnorm_kernel<<<(N * C + 255) / 256, 256, 0, stream>>>(agg, st + 2 * 256, out);
}